// Round 16
// baseline (383.152 us; speedup 1.0000x reference)
//
#include <hip/hip_runtime.h>
#include <stdint.h>
#include <stddef.h>

// ---------------------------------------------------------------------------
// BoundingBox loss processor:
//   filter (maxconf > 0.6) -> sort by class-0 score desc (stable, idx asc)
//   -> greedy NMS (IoU > 0.5 suppress) -> per-class top-20 over kept
//   -> smooth-L1 vs targets + focal CE on (class0 top-20 > 0.5) -> /M
//
// Journal: R10 involved-set greedy 601->197. R13 register topk. R14 pre-OR
// atomics (conflicts 28K->136). R15 128-row chunks: k_scan 188->139, total
// 381. R16: SPARSITY filter — suppression is rare (M~F, few hundred set bits
// in 8M mask words), so k_mask publishes per-(row,16-word-group) nonzero
// bits (grp, 8KB); k_scan phase 1 loads only flagged pairs (~0-2/chunk vs
// 8192). Zero words OR nothing -> rem evolution bit-identical.
// ---------------------------------------------------------------------------

#define NCAP 8192
#define WROW (NCAP / 64)   // 128 u64 words per mask row

typedef unsigned long long u64;

// ---------------- workspace layout (all offsets 16-byte aligned) -----------
constexpr size_t OFF_CNT   = 0;                               // 2 x u32: [0]=F, [1]=M
constexpr size_t OFF_KEYS  = 256;                             // (unused now)
constexpr size_t OFF_SX1   = OFF_KEYS + 8ull * NCAP;          // f32[NCAP]
constexpr size_t OFF_SY1   = OFF_SX1 + 4ull * NCAP;
constexpr size_t OFF_SX2   = OFF_SY1 + 4ull * NCAP;
constexpr size_t OFF_SY2   = OFF_SX2 + 4ull * NCAP;
constexpr size_t OFF_AREA  = OFF_SY2 + 4ull * NCAP;
constexpr size_t OFF_SORIG = OFF_AREA + 4ull * NCAP;          // u32[NCAP]
constexpr size_t OFF_KEEPS = OFF_SORIG + 4ull * NCAP;         // u32[NCAP]
constexpr size_t OFF_KORIG = OFF_KEEPS + 4ull * NCAP;         // u32[NCAP] (unused)
constexpr size_t OFF_TOPV  = OFF_KORIG + 4ull * NCAP;         // f32[1024]
constexpr size_t OFF_TOPI  = OFF_TOPV + 4096;                 // i32[1024]
constexpr size_t OFF_GRP   = OFF_TOPI + 4096;                 // u32[2048] = 8 KB nz bitmap
constexpr size_t OFF_DIAG2 = OFF_GRP + 8192;                  // u64[2*NCAP] = 128 KB
constexpr size_t OFF_MASK  = OFF_DIAG2 + 16ull * NCAP;        // u64[NCAP*WROW] = 8 MB
constexpr size_t WS_NEED_MASK = OFF_MASK + 8ull * NCAP * WROW;

// wave-wide OR of a u64 (6 butterfly steps, 2x32b shuffles each)
__device__ __forceinline__ u64 wave_or64(u64 x) {
#pragma unroll
  for (int off = 1; off < 64; off <<= 1) {
    unsigned lo = __shfl_xor((unsigned)x, off);
    unsigned hi = __shfl_xor((unsigned)(x >> 32), off);
    x |= ((u64)hi << 32) | lo;
  }
  return x;
}

// ---------------- kernels ---------------------------------------------------

// ---------------------------------------------------------------------------
// Fused filter + bitonic sort + gather, one block of 1024 threads (R11).
// Epilogue also zero-inits the grp nonzero bitmap for k_mask's atomics.
// ---------------------------------------------------------------------------
#define SS1(M)                                                              \
  { int tt = base + (M) * 64 + l;                                           \
    u64 a = e[M];                                                           \
    unsigned slo = __shfl_xor((unsigned)a, (int)jj);                        \
    unsigned shi = __shfl_xor((unsigned)(a >> 32), (int)jj);                \
    u64 b = ((u64)shi << 32) | slo;                                         \
    bool up = ((tt & bk) == 0);                                             \
    bool lowr = ((l & (int)jj) == 0);                                       \
    bool tmin = (up == lowr);                                               \
    bool agtb = (a > b);                                                    \
    e[M] = (tmin == agtb) ? b : a; }

#define SSTEP() { SS1(0) SS1(1) SS1(2) SS1(3) SS1(4) SS1(5) SS1(6) SS1(7) }

#define CSW(A, B)                                                           \
  { int tt = base + (A) * 64 + l;                                           \
    bool up = ((tt & bk) == 0);                                             \
    u64 xa = e[A], xb = e[B];                                               \
    bool sw = up ? (xa > xb) : (xa < xb);                                   \
    e[A] = sw ? xb : xa; e[B] = sw ? xa : xb; }

#define RSTEP4() { CSW(0,4) CSW(1,5) CSW(2,6) CSW(3,7) }
#define RSTEP2() { CSW(0,2) CSW(1,3) CSW(4,6) CSW(5,7) }
#define RSTEP1() { CSW(0,1) CSW(2,3) CSW(4,5) CSW(6,7) }

__global__ __launch_bounds__(1024) void k_sortf(
    const float* __restrict__ conf, const float* __restrict__ loc,
    int N, int C, unsigned int* __restrict__ cnt,
    float* __restrict__ sx1, float* __restrict__ sy1,
    float* __restrict__ sx2, float* __restrict__ sy2,
    float* __restrict__ sarea, unsigned int* __restrict__ sorig,
    unsigned int* __restrict__ grp32) {
  __shared__ u64 sk[NCAP];  // 64 KiB (only used in j>=512 sessions)
  __shared__ int wsum[16];
  const int tid = threadIdx.x;
  const int w = tid >> 6, l = tid & 63;
  const int base = w * 512;
  u64 e[8];

  // zero the nonzero-group bitmap (read/atomicOr'd by k_mask, later kernels)
  for (int i = tid; i < 2048; i += 1024) grp32[i] = 0u;

  // build keys: desc(class0 score) | row; invalid rows sort last
#pragma unroll
  for (int m = 0; m < 8; ++m) {
    int row = base + m * 64 + l;
    u64 key;
    if (row < N) {
      const float* cr = conf + (size_t)row * C;
      float mx = cr[0];
      for (int c = 1; c < C; ++c) mx = fmaxf(mx, cr[c]);
      unsigned int k32;
      if (mx > 0.6f) {
        union { float f; unsigned int u; } s; s.f = cr[0];
        unsigned int u = s.u;
        u = (u & 0x80000000u) ? ~u : (u | 0x80000000u);  // monotone map
        k32 = ~u;                                        // descending
        if (k32 == 0xFFFFFFFFu) k32 = 0xFFFFFFFEu;       // reserve invalid
      } else {
        k32 = 0xFFFFFFFFu;
      }
      key = ((u64)k32 << 32) | (unsigned int)row;
    } else {
      key = ((u64)0xFFFFFFFFu << 32);
    }
    e[m] = key;
  }

  for (unsigned bk = 2; bk <= NCAP; bk <<= 1) {
    unsigned j = bk >> 1;
    if (j >= 512) {
      // LDS session for steps j = bk/2 .. 512
#pragma unroll
      for (int m = 0; m < 8; ++m) sk[base + m * 64 + l] = e[m];
      __syncthreads();
      for (unsigned j2 = bk >> 1; j2 >= 512; j2 >>= 1) {
        for (int tl = tid; tl < NCAP; tl += 1024) {
          unsigned p = (unsigned)tl ^ j2;
          if (p > (unsigned)tl) {
            bool up = ((tl & bk) == 0);
            u64 x = sk[tl], y = sk[p];
            bool sw = up ? (x > y) : (x < y);
            if (sw) { sk[tl] = y; sk[p] = x; }
          }
        }
        __syncthreads();
      }
#pragma unroll
      for (int m = 0; m < 8; ++m) e[m] = sk[base + m * 64 + l];
      __syncthreads();   // protect sk reads from next session's writes
      j = 256;
    }
    if (j == 256) { RSTEP4(); j = 128; }
    if (j == 128) { RSTEP2(); j = 64; }
    if (j == 64)  { RSTEP1(); j = 32; }
    for (unsigned jj = j; jj >= 1; jj >>= 1) SSTEP();
  }

  // epilogue: count valid + fused gather
  int cv = 0;
#pragma unroll
  for (int m = 0; m < 8; ++m) {
    int idx = base + m * 64 + l;
    u64 key = e[m];
    if ((key >> 32) != 0xFFFFFFFFull) ++cv;
    unsigned row = (unsigned)(key & 0xFFFFFFFFull);
    const float* b = loc + (size_t)row * 4;
    float x1 = b[0], y1 = b[1], x2 = b[2], y2 = b[3];
    sx1[idx] = x1; sy1[idx] = y1; sx2[idx] = x2; sy2[idx] = y2;
    sarea[idx] = (x2 - x1) * (y2 - y1);   // numpy op order, no FMA hazard
    sorig[idx] = row;
  }
  for (int off = 32; off; off >>= 1) cv += __shfl_down(cv, off);
  if (l == 0) wsum[w] = cv;
  __syncthreads();
  if (tid == 0) {
    int s = 0;
    for (int i = 0; i < 16; ++i) s += wsum[i];
    cnt[0] = (unsigned int)s;
  }
}

// Pairwise IoU>0.5 bitmask, 64x64 tiles, 1 wave per block.
// Skip by < (bx & ~1) (never consumed). Diagonal-super blocks also write the
// diagG2 strip. NEW (R16): nonzero tiles flag bit (by>>4) of row i's byte in
// grp32 — k_scan loads only flagged 16-word groups.
__global__ __launch_bounds__(64) void k_mask(
    const float* __restrict__ sx1, const float* __restrict__ sy1,
    const float* __restrict__ sx2, const float* __restrict__ sy2,
    const float* __restrict__ sarea,
    u64* __restrict__ mask, u64* __restrict__ diagG2,
    unsigned int* __restrict__ grp32) {
  if (blockIdx.y < (blockIdx.x & ~1u)) return;
  __shared__ float jx1[64], jy1[64], jx2[64], jy2[64], ja[64];
  int t = threadIdx.x;
  int jbase = blockIdx.y * 64;
  jx1[t] = sx1[jbase + t]; jy1[t] = sy1[jbase + t];
  jx2[t] = sx2[jbase + t]; jy2[t] = sy2[jbase + t];
  ja[t]  = sarea[jbase + t];
  __syncthreads();
  int i = blockIdx.x * 64 + t;
  float xi1 = sx1[i], yi1 = sy1[i], xi2 = sx2[i], yi2 = sy2[i], ai = sarea[i];
  u64 bits = 0ULL;
#pragma unroll 8
  for (int jj = 0; jj < 64; ++jj) {
    float xx1 = fmaxf(xi1, jx1[jj]);
    float yy1 = fmaxf(yi1, jy1[jj]);
    float xx2 = fminf(xi2, jx2[jj]);
    float yy2 = fminf(yi2, jy2[jj]);
    float w = fmaxf(xx2 - xx1, 0.0f);
    float h = fmaxf(yy2 - yy1, 0.0f);
    float inter = w * h;
    float den = ai + ja[jj] - inter;   // (ai + aj) - inter, numpy order
    float iou = inter / den;           // IEEE div; 0/0 -> NaN -> compare false
    if (iou > 0.5f) bits |= (1ULL << jj);
  }
  mask[(size_t)i * WROW + blockIdx.y] = bits;
  if ((blockIdx.y >> 1) == (blockIdx.x >> 1))
    diagG2[(size_t)(blockIdx.y & 1) * NCAP + i] = bits;
  if (bits)
    atomicOr(&grp32[i >> 2], 1u << (((i & 3) << 3) + (blockIdx.y >> 4)));
}

// ---------------------------------------------------------------------------
// Chunked greedy scan — R15 structure (128-row chunks, diag strip in LDS,
// chained involved-set greedys, pre-OR atomics) + R16 sparsity filter:
// phase 1 loads a word-pair only if its (row, 16-word-group) is flagged in
// grp (staged in LDS once). Zero words OR nothing -> bit-identical keeps.
// ---------------------------------------------------------------------------
__global__ __launch_bounds__(1024) void k_scan(
    const u64* __restrict__ mask,
    const u64* __restrict__ diagG2,
    const unsigned int* __restrict__ grp32,
    unsigned int* __restrict__ cnt,
    unsigned int* __restrict__ keeps) {
  __shared__ u64 ldsDiag[2 * NCAP];       // 128 KB
  __shared__ unsigned int gnz[2048];      // 8 KB: nz byte per row, bit q per 16w
  __shared__ u64 rem[WROW];               // removed-set (1 KB)
  __shared__ u64 ldsKA, ldsKB;
  const int tid = threadIdx.x;
  const int F = (int)cnt[0];
  const int nch = (F + 127) >> 7;
  const ulonglong2* __restrict__ m2 = (const ulonglong2*)mask;  // 64 pairs/row

  for (int i = tid; i < 2 * NCAP; i += 1024) ldsDiag[i] = diagG2[i];
  for (int i = tid; i < 2048; i += 1024) gnz[i] = grp32[i];
  for (int w = tid; w < WROW; w += 1024) rem[w] = 0;

  const int p0 = tid & 63;    // pair index (words 2p0, 2p0+1) of held rows
  const int g0 = tid >> 6;    // row group: rows g0 + 16k (k<8) of each chunk
  const int bitq = p0 >> 3;   // 16-word group of this pair
  int K = 0;
  __syncthreads();            // staging + rem init visible

  for (int H = 0; H < nch; ++H) {
    const size_t gb = (size_t)H * 8192;   // chunk = 8192 linear 16B units
    const int base = H << 7;
    const bool ld = (p0 > H);             // both words >= 2H+2
    ulonglong2 v0 = {0,0}, v1 = {0,0}, v2 = {0,0}, v3 = {0,0},
               v4 = {0,0}, v5 = {0,0}, v6 = {0,0}, v7 = {0,0};
    if (ld) {
      // load only pairs whose 16-word group is flagged nonzero for that row
#define NZROW(RR) ((gnz[(RR) >> 2] >> ((((RR) & 3) << 3) + bitq)) & 1u)
      int r0 = base + g0;
      if (NZROW(r0))       v0 = m2[gb + tid];
      if (NZROW(r0 + 16))  v1 = m2[gb + tid + 1024];
      if (NZROW(r0 + 32))  v2 = m2[gb + tid + 2048];
      if (NZROW(r0 + 48))  v3 = m2[gb + tid + 3072];
      if (NZROW(r0 + 64))  v4 = m2[gb + tid + 4096];
      if (NZROW(r0 + 80))  v5 = m2[gb + tid + 5120];
      if (NZROW(r0 + 96))  v6 = m2[gb + tid + 6144];
      if (NZROW(r0 + 112)) v7 = m2[gb + tid + 7168];
#undef NZROW
    }
    __syncthreads();   // prev chunk's rem ORs visible before greedy

    if (tid < 64) {
      u64 DA = ldsDiag[base + tid];                 // plane 0: word 2H, A rows
      u64 AB = ldsDiag[NCAP + base + tid];          // plane 1: word 2H+1, A rows
      u64 DB = ldsDiag[NCAP + base + 64 + tid];     // plane 1: word 2H+1, B rows
      int remrows = F - base;
      u64 validA = (remrows >= 64) ? ~0ull : ((1ull << remrows) - 1ull);
      int r2 = remrows - 64;
      u64 validB = (r2 >= 64) ? ~0ull : ((r2 <= 0) ? 0ull : ((1ull << r2) - 1ull));

      // ---- sub-greedy A (R10 involved-set shortcut) ----
      u64 sup0 = rem[2 * H];
      u64 DfwdA = (tid < 63) ? (DA & (~0ull << (tid + 1))) : 0ull;
      u64 undec = validA & ~sup0;
      u64 dmask = ((undec >> tid) & 1ull) ? DfwdA : 0ull;
      u64 vuln = wave_or64(dmask);
      u64 dang = __ballot(dmask != 0ull);
      u64 involved = (dang | vuln) & undec;
      u64 keepA = undec & ~involved;
      u64 und2 = involved;
      {
        unsigned Flo = (unsigned)DfwdA, Fhi = (unsigned)(DfwdA >> 32);
        while (und2) {
          int rr = __builtin_ctzll(und2);
          keepA |= 1ull << rr;
          unsigned dlo = __builtin_amdgcn_readlane(Flo, rr);
          unsigned dhi = __builtin_amdgcn_readlane(Fhi, rr);
          und2 &= ~((((u64)dhi << 32) | (u64)dlo) | (1ull << rr));
        }
      }

      // ---- A -> B suppression, then sub-greedy B ----
      u64 abm = ((keepA >> tid) & 1ull) ? AB : 0ull;
      u64 supB = rem[2 * H + 1] | wave_or64(abm);
      u64 DfwdB = (tid < 63) ? (DB & (~0ull << (tid + 1))) : 0ull;
      u64 undecB = validB & ~supB;
      u64 dmaskB = ((undecB >> tid) & 1ull) ? DfwdB : 0ull;
      u64 vulnB = wave_or64(dmaskB);
      u64 dangB = __ballot(dmaskB != 0ull);
      u64 involvedB = (dangB | vulnB) & undecB;
      u64 keepB = undecB & ~involvedB;
      u64 und2B = involvedB;
      {
        unsigned Flo = (unsigned)DfwdB, Fhi = (unsigned)(DfwdB >> 32);
        while (und2B) {
          int rr = __builtin_ctzll(und2B);
          keepB |= 1ull << rr;
          unsigned dlo = __builtin_amdgcn_readlane(Flo, rr);
          unsigned dhi = __builtin_amdgcn_readlane(Fhi, rr);
          und2B &= ~((((u64)dhi << 32) | (u64)dlo) | (1ull << rr));
        }
      }

      if (tid == 0) { ldsKA = keepA; ldsKB = keepB; }
      // parallel keeps store, ascending order via mbcnt prefix
      int pcA = __popcll(keepA);
      {
        unsigned klo = (unsigned)keepA, khi = (unsigned)(keepA >> 32);
        int pre = __builtin_amdgcn_mbcnt_hi(khi, __builtin_amdgcn_mbcnt_lo(klo, 0));
        if ((keepA >> tid) & 1ull) keeps[K + pre] = (unsigned)(base + tid);
      }
      {
        unsigned klo = (unsigned)keepB, khi = (unsigned)(keepB >> 32);
        int pre = __builtin_amdgcn_mbcnt_hi(khi, __builtin_amdgcn_mbcnt_lo(klo, 0));
        if ((keepB >> tid) & 1ull) keeps[K + pcA + pre] = (unsigned)(base + 64 + tid);
      }
      K += pcA + __popcll(keepB);
    }
    __syncthreads();   // ldsKA/ldsKB visible

    const u64 keepA = ldsKA, keepB = ldsKB;
    if (ld && (keepA | keepB)) {
      u64 ax = 0, ay = 0;                  // register pre-OR (R14)
      if ((keepA >> g0) & 1ull)        { ax |= v0.x; ay |= v0.y; }
      if ((keepA >> (g0+16)) & 1ull)   { ax |= v1.x; ay |= v1.y; }
      if ((keepA >> (g0+32)) & 1ull)   { ax |= v2.x; ay |= v2.y; }
      if ((keepA >> (g0+48)) & 1ull)   { ax |= v3.x; ay |= v3.y; }
      if ((keepB >> g0) & 1ull)        { ax |= v4.x; ay |= v4.y; }
      if ((keepB >> (g0+16)) & 1ull)   { ax |= v5.x; ay |= v5.y; }
      if ((keepB >> (g0+32)) & 1ull)   { ax |= v6.x; ay |= v6.y; }
      if ((keepB >> (g0+48)) & 1ull)   { ax |= v7.x; ay |= v7.y; }
      const int w0 = 2 * p0;
      if (ax) atomicOr(&rem[w0], ax);
      if (ay) atomicOr(&rem[w0 + 1], ay);
    }
    // next iteration's first barrier orders these ORs before rem reads
  }
  if (tid == 0) cnt[1] = (unsigned int)K;
}

// Fallback (small workspace): on-the-fly IoU greedy scan in one block.
__global__ __launch_bounds__(256) void k_scan_nomask(
    const float* __restrict__ sx1, const float* __restrict__ sy1,
    const float* __restrict__ sx2, const float* __restrict__ sy2,
    const float* __restrict__ sarea,
    unsigned int* __restrict__ cnt,
    unsigned int* __restrict__ keeps) {
  __shared__ unsigned char sup[NCAP];
  __shared__ int sK;
  int tid = threadIdx.x;
  int F = (int)cnt[0];
  for (int j = tid; j < NCAP; j += 256) sup[j] = 0;
  if (tid == 0) sK = 0;
  __syncthreads();
  for (int i = 0; i < F; ++i) {
    if (!sup[i]) {
      if (tid == 0) keeps[sK++] = (unsigned int)i;
      float xi1 = sx1[i], yi1 = sy1[i], xi2 = sx2[i], yi2 = sy2[i], ai = sarea[i];
      for (int j = i + 1 + tid; j < F; j += 256) {
        if (sup[j]) continue;
        float xx1 = fmaxf(xi1, sx1[j]);
        float yy1 = fmaxf(yi1, sy1[j]);
        float xx2 = fminf(xi2, sx2[j]);
        float yy2 = fminf(yi2, sy2[j]);
        float w = fmaxf(xx2 - xx1, 0.0f);
        float h = fmaxf(yy2 - yy1, 0.0f);
        float inter = w * h;
        float iou = inter / (ai + sarea[j] - inter);
        if (iou > 0.5f) sup[j] = 1;
      }
    }
    __syncthreads();
  }
  if (tid == 0) cnt[1] = (unsigned int)sK;
}

// ---------------------------------------------------------------------------
// Per class: top-KT over M kept boxes, REGISTER-RESIDENT (R13, unchanged).
// ---------------------------------------------------------------------------
__global__ __launch_bounds__(1024) void k_topk(
    const float* __restrict__ conf,
    const unsigned int* __restrict__ sorig,
    const unsigned int* __restrict__ keeps,
    const unsigned int* __restrict__ cnt,
    int C, int KT,
    float* __restrict__ topv, int* __restrict__ topi) {
  __shared__ float wlv[16];
  __shared__ int wli[16];
  __shared__ float ldsWv;
  __shared__ int ldsWj;
  const int tid = threadIdx.x;
  const int lane = tid & 63;
  const int wv_ = tid >> 6;
  const int c = blockIdx.x;
  const int M = (int)cnt[1];

  const float NEG = -3.402823466e+38f;
  float v[8];
#pragma unroll
  for (int k = 0; k < 8; ++k) {
    int j = tid + (k << 10);
    v[k] = (j < M) ? conf[(size_t)sorig[keeps[j]] * C + c] : NEG;
  }
  // thread-local argmax (global index tie-break: smaller k first is smaller j)
  float bv = NEG; int bk_ = -1;
#pragma unroll
  for (int k = 0; k < 8; ++k)
    if (v[k] > bv) { bv = v[k]; bk_ = k; }
  int bj = (bk_ >= 0) ? (tid + (bk_ << 10)) : 0x7FFFFFFF;
  if (bv == NEG) bj = 0x7FFFFFFF;

  for (int t = 0; t < KT; ++t) {
    // wave reduce
    float rv = bv; int rj = bj;
#pragma unroll
    for (int off = 32; off; off >>= 1) {
      float v2 = __shfl_down(rv, off);
      int   j2 = __shfl_down(rj, off);
      if (v2 > rv || (v2 == rv && j2 < rj)) { rv = v2; rj = j2; }
    }
    if (lane == 0) { wlv[wv_] = rv; wli[wv_] = rj; }
    __syncthreads();
    if (wv_ == 0) {
      float fv = (lane < 16) ? wlv[lane] : NEG;
      int   fj = (lane < 16) ? wli[lane] : 0x7FFFFFFF;
#pragma unroll
      for (int off = 32; off; off >>= 1) {
        float v2 = __shfl_down(fv, off);
        int   j2 = __shfl_down(fj, off);
        if (v2 > fv || (v2 == fv && j2 < fj)) { fv = v2; fj = j2; }
      }
      if (lane == 0) {
        ldsWv = fv; ldsWj = fj;
        topv[c * KT + t] = fv;
        topi[c * KT + t] = (fj == 0x7FFFFFFF) ? 0 : fj;  // M<KT safety
      }
    }
    __syncthreads();
    const int wj = ldsWj;
    if (wj != 0x7FFFFFFF && (wj & 1023) == tid) {
      int kk = wj >> 10;
#pragma unroll
      for (int k = 0; k < 8; ++k)
        if (k == kk) v[k] = NEG;
      bv = NEG; bk_ = -1;
#pragma unroll
      for (int k = 0; k < 8; ++k)
        if (v[k] > bv) { bv = v[k]; bk_ = k; }
      bj = (bk_ >= 0) ? (tid + (bk_ << 10)) : 0x7FFFFFFF;
      if (bv == NEG) bj = 0x7FFFFFFF;
    }
  }
}

// Final scalar: smooth-L1 over (KT, C, 4) gathered boxes + focal CE on
// (class0 top-KT > 0.5), divided by M.
__global__ __launch_bounds__(256) void k_loss(
    const float* __restrict__ loc, const float* __restrict__ tb,
    const int* __restrict__ labels,
    const unsigned int* __restrict__ sorig,
    const unsigned int* __restrict__ keeps,
    const float* __restrict__ topv, const int* __restrict__ topi,
    const unsigned int* __restrict__ cnt, int C, int KT,
    float* __restrict__ out) {
  __shared__ float red[256];
  int tid = threadIdx.x;
  int F = (int)cnt[0];
  int M = (int)cnt[1];
  if (F == 0 || M == 0) {
    if (tid == 0) out[0] = 0.001f;
    return;
  }
  int total = KT * C * 4;
  float part = 0.0f;
  for (int e = tid; e < total; e += 256) {
    int d = e & 3;
    int q = e >> 2;
    int c = q % C;
    int i = q / C;
    int j = topi[c * KT + i];
    unsigned int orow = sorig[keeps[j]];
    float pred = loc[(size_t)orow * 4 + d];
    float tg = tb[c * 4 + d];
    float dd = fabsf(pred - tg);
    part += (dd < 1.0f) ? (0.5f * dd * dd) : (dd - 0.5f);
  }
  red[tid] = part;
  __syncthreads();
  for (int s = 128; s > 0; s >>= 1) {
    if (tid < s) red[tid] += red[tid + s];
    __syncthreads();
  }
  if (tid == 0) {
    float loc_loss = red[0];
    float mx = -3.402823466e+38f;
    for (int i = 0; i < KT; ++i) {
      float x = (topv[i] > 0.5f) ? 1.0f : 0.0f;   // class 0 column
      mx = fmaxf(mx, x);
    }
    float ssum = 0.0f;
    for (int i = 0; i < KT; ++i) {
      float x = (topv[i] > 0.5f) ? 1.0f : 0.0f;
      ssum += expf(x - mx);
    }
    float lse = mx + logf(ssum);
    float ce = 0.0f;
    for (int i = 0; i < KT; ++i) {
      float x = (topv[i] > 0.5f) ? 1.0f : 0.0f;
      ce += (float)labels[i] * (x - lse);
    }
    ce = -ce;
    float pt = expf(-ce);
    float om = 1.0f - pt;
    float conf_loss = 0.25f * om * om * ce;   // ALPHA=0.25, GAMMA=2
    out[0] = (loc_loss + conf_loss) / (float)M;
  }
}

// ---------------- host ------------------------------------------------------

extern "C" void kernel_launch(void* const* d_in, const int* in_sizes, int n_in,
                              void* d_out, int out_size, void* d_ws, size_t ws_size,
                              hipStream_t stream) {
  (void)n_in; (void)out_size;
  const float* loc    = (const float*)d_in[0];
  const float* conf   = (const float*)d_in[1];
  const float* tb     = (const float*)d_in[2];
  const int*   labels = (const int*)d_in[3];
  float* out = (float*)d_out;

  int N = in_sizes[0] / 4;
  if (N > NCAP) N = NCAP;
  int C  = (N > 0) ? (in_sizes[1] / N) : 20;
  int KT = in_sizes[3];

  char* ws = (char*)d_ws;
  unsigned int* cnt   = (unsigned int*)(ws + OFF_CNT);
  float*        sx1   = (float*)(ws + OFF_SX1);
  float*        sy1   = (float*)(ws + OFF_SY1);
  float*        sx2   = (float*)(ws + OFF_SX2);
  float*        sy2   = (float*)(ws + OFF_SY2);
  float*        sarea = (float*)(ws + OFF_AREA);
  unsigned int* sorig = (unsigned int*)(ws + OFF_SORIG);
  unsigned int* keeps = (unsigned int*)(ws + OFF_KEEPS);
  float*        topv  = (float*)(ws + OFF_TOPV);
  int*          topi  = (int*)(ws + OFF_TOPI);
  unsigned int* grp32 = (unsigned int*)(ws + OFF_GRP);
  u64*          diag2 = (u64*)(ws + OFF_DIAG2);
  u64*          mask  = (u64*)(ws + OFF_MASK);

  bool use_mask = (ws_size >= WS_NEED_MASK);

  k_sortf<<<1, 1024, 0, stream>>>(conf, loc, N, C, cnt,
                                  sx1, sy1, sx2, sy2, sarea, sorig, grp32);
  if (use_mask) {
    k_mask<<<dim3(WROW, WROW), 64, 0, stream>>>(sx1, sy1, sx2, sy2, sarea,
                                                mask, diag2, grp32);
    k_scan<<<1, 1024, 0, stream>>>(mask, diag2, grp32, cnt, keeps);
  } else {
    k_scan_nomask<<<1, 256, 0, stream>>>(sx1, sy1, sx2, sy2, sarea, cnt, keeps);
  }
  k_topk<<<C, 1024, 0, stream>>>(conf, sorig, keeps, cnt, C, KT, topv, topi);
  k_loss<<<1, 256, 0, stream>>>(loc, tb, labels, sorig, keeps, topv, topi, cnt, C, KT, out);
}

// Round 17
// 375.751 us; speedup vs baseline: 1.0197x; 1.0197x over previous
//
#include <hip/hip_runtime.h>
#include <stdint.h>
#include <stddef.h>

// ---------------------------------------------------------------------------
// BoundingBox loss processor:
//   filter (maxconf > 0.6) -> sort by class-0 score desc (stable, idx asc)
//   -> greedy NMS (IoU > 0.5 suppress) -> per-class top-20 over kept
//   -> smooth-L1 vs targets + focal CE on (class0 top-20 > 0.5) -> /M
//
// Journal: R10 involved-set greedy. R13 register topk. R14 pre-OR atomics.
// R15 128-row chunks: 139us. R16 sparsity filter: FETCH 2.3MB->0.4MB but
// 147us — proved dense phase-1 loads are FREE (hidden behind 2 barriers);
// critical path = wave-0 serial segment between barriers. R17: revert gnz,
// shorten wave-0 segment: interleaved diag (b128), sup pair b128 (5 LDS
// reads -> 3), keeps stores offloaded to wave 1 in phase 3.
// ---------------------------------------------------------------------------

#define NCAP 8192
#define WROW (NCAP / 64)   // 128 u64 words per mask row

typedef unsigned long long u64;

// ---------------- workspace layout (all offsets 16-byte aligned) -----------
constexpr size_t OFF_CNT   = 0;                               // 2 x u32: [0]=F, [1]=M
constexpr size_t OFF_KEYS  = 256;                             // (unused now)
constexpr size_t OFF_SX1   = OFF_KEYS + 8ull * NCAP;          // f32[NCAP]
constexpr size_t OFF_SY1   = OFF_SX1 + 4ull * NCAP;
constexpr size_t OFF_SX2   = OFF_SY1 + 4ull * NCAP;
constexpr size_t OFF_SY2   = OFF_SX2 + 4ull * NCAP;
constexpr size_t OFF_AREA  = OFF_SY2 + 4ull * NCAP;
constexpr size_t OFF_SORIG = OFF_AREA + 4ull * NCAP;          // u32[NCAP]
constexpr size_t OFF_KEEPS = OFF_SORIG + 4ull * NCAP;         // u32[NCAP]
constexpr size_t OFF_KORIG = OFF_KEEPS + 4ull * NCAP;         // u32[NCAP] (unused)
constexpr size_t OFF_TOPV  = OFF_KORIG + 4ull * NCAP;         // f32[1024]
constexpr size_t OFF_TOPI  = OFF_TOPV + 4096;                 // i32[1024]
constexpr size_t OFF_DIAG2 = OFF_TOPI + 4096;                 // u64[2*NCAP] = 128 KB, interleaved
constexpr size_t OFF_MASK  = OFF_DIAG2 + 16ull * NCAP;        // u64[NCAP*WROW] = 8 MB
constexpr size_t WS_NEED_MASK = OFF_MASK + 8ull * NCAP * WROW;

// wave-wide OR of a u64 (6 butterfly steps, 2x32b shuffles each)
__device__ __forceinline__ u64 wave_or64(u64 x) {
#pragma unroll
  for (int off = 1; off < 64; off <<= 1) {
    unsigned lo = __shfl_xor((unsigned)x, off);
    unsigned hi = __shfl_xor((unsigned)(x >> 32), off);
    x |= ((u64)hi << 32) | lo;
  }
  return x;
}

// ---------------- kernels ---------------------------------------------------

// ---------------------------------------------------------------------------
// Fused filter + bitonic sort + gather, one block of 1024 threads (R11).
// ---------------------------------------------------------------------------
#define SS1(M)                                                              \
  { int tt = base + (M) * 64 + l;                                           \
    u64 a = e[M];                                                           \
    unsigned slo = __shfl_xor((unsigned)a, (int)jj);                        \
    unsigned shi = __shfl_xor((unsigned)(a >> 32), (int)jj);                \
    u64 b = ((u64)shi << 32) | slo;                                         \
    bool up = ((tt & bk) == 0);                                             \
    bool lowr = ((l & (int)jj) == 0);                                       \
    bool tmin = (up == lowr);                                               \
    bool agtb = (a > b);                                                    \
    e[M] = (tmin == agtb) ? b : a; }

#define SSTEP() { SS1(0) SS1(1) SS1(2) SS1(3) SS1(4) SS1(5) SS1(6) SS1(7) }

#define CSW(A, B)                                                           \
  { int tt = base + (A) * 64 + l;                                           \
    bool up = ((tt & bk) == 0);                                             \
    u64 xa = e[A], xb = e[B];                                               \
    bool sw = up ? (xa > xb) : (xa < xb);                                   \
    e[A] = sw ? xb : xa; e[B] = sw ? xa : xb; }

#define RSTEP4() { CSW(0,4) CSW(1,5) CSW(2,6) CSW(3,7) }
#define RSTEP2() { CSW(0,2) CSW(1,3) CSW(4,6) CSW(5,7) }
#define RSTEP1() { CSW(0,1) CSW(2,3) CSW(4,5) CSW(6,7) }

__global__ __launch_bounds__(1024) void k_sortf(
    const float* __restrict__ conf, const float* __restrict__ loc,
    int N, int C, unsigned int* __restrict__ cnt,
    float* __restrict__ sx1, float* __restrict__ sy1,
    float* __restrict__ sx2, float* __restrict__ sy2,
    float* __restrict__ sarea, unsigned int* __restrict__ sorig) {
  __shared__ u64 sk[NCAP];  // 64 KiB (only used in j>=512 sessions)
  __shared__ int wsum[16];
  const int tid = threadIdx.x;
  const int w = tid >> 6, l = tid & 63;
  const int base = w * 512;
  u64 e[8];

  // build keys: desc(class0 score) | row; invalid rows sort last
#pragma unroll
  for (int m = 0; m < 8; ++m) {
    int row = base + m * 64 + l;
    u64 key;
    if (row < N) {
      const float* cr = conf + (size_t)row * C;
      float mx = cr[0];
      for (int c = 1; c < C; ++c) mx = fmaxf(mx, cr[c]);
      unsigned int k32;
      if (mx > 0.6f) {
        union { float f; unsigned int u; } s; s.f = cr[0];
        unsigned int u = s.u;
        u = (u & 0x80000000u) ? ~u : (u | 0x80000000u);  // monotone map
        k32 = ~u;                                        // descending
        if (k32 == 0xFFFFFFFFu) k32 = 0xFFFFFFFEu;       // reserve invalid
      } else {
        k32 = 0xFFFFFFFFu;
      }
      key = ((u64)k32 << 32) | (unsigned int)row;
    } else {
      key = ((u64)0xFFFFFFFFu << 32);
    }
    e[m] = key;
  }

  for (unsigned bk = 2; bk <= NCAP; bk <<= 1) {
    unsigned j = bk >> 1;
    if (j >= 512) {
      // LDS session for steps j = bk/2 .. 512
#pragma unroll
      for (int m = 0; m < 8; ++m) sk[base + m * 64 + l] = e[m];
      __syncthreads();
      for (unsigned j2 = bk >> 1; j2 >= 512; j2 >>= 1) {
        for (int tl = tid; tl < NCAP; tl += 1024) {
          unsigned p = (unsigned)tl ^ j2;
          if (p > (unsigned)tl) {
            bool up = ((tl & bk) == 0);
            u64 x = sk[tl], y = sk[p];
            bool sw = up ? (x > y) : (x < y);
            if (sw) { sk[tl] = y; sk[p] = x; }
          }
        }
        __syncthreads();
      }
#pragma unroll
      for (int m = 0; m < 8; ++m) e[m] = sk[base + m * 64 + l];
      __syncthreads();   // protect sk reads from next session's writes
      j = 256;
    }
    if (j == 256) { RSTEP4(); j = 128; }
    if (j == 128) { RSTEP2(); j = 64; }
    if (j == 64)  { RSTEP1(); j = 32; }
    for (unsigned jj = j; jj >= 1; jj >>= 1) SSTEP();
  }

  // epilogue: count valid + fused gather
  int cv = 0;
#pragma unroll
  for (int m = 0; m < 8; ++m) {
    int idx = base + m * 64 + l;
    u64 key = e[m];
    if ((key >> 32) != 0xFFFFFFFFull) ++cv;
    unsigned row = (unsigned)(key & 0xFFFFFFFFull);
    const float* b = loc + (size_t)row * 4;
    float x1 = b[0], y1 = b[1], x2 = b[2], y2 = b[3];
    sx1[idx] = x1; sy1[idx] = y1; sx2[idx] = x2; sy2[idx] = y2;
    sarea[idx] = (x2 - x1) * (y2 - y1);   // numpy op order, no FMA hazard
    sorig[idx] = row;
  }
  for (int off = 32; off; off >>= 1) cv += __shfl_down(cv, off);
  if (l == 0) wsum[w] = cv;
  __syncthreads();
  if (tid == 0) {
    int s = 0;
    for (int i = 0; i < 16; ++i) s += wsum[i];
    cnt[0] = (unsigned int)s;
  }
}

// Pairwise IoU>0.5 bitmask, 64x64 tiles, 1 wave per block.
// Skip by < (bx & ~1) (never consumed). Diagonal-super blocks write the
// INTERLEAVED diag strip: diagI[2*i + (by&1)] — (word2H, word2H+1) adjacent
// per row so k_scan's wave 0 reads both with one ds_read_b128 (R17).
__global__ __launch_bounds__(64) void k_mask(
    const float* __restrict__ sx1, const float* __restrict__ sy1,
    const float* __restrict__ sx2, const float* __restrict__ sy2,
    const float* __restrict__ sarea,
    u64* __restrict__ mask, u64* __restrict__ diagI) {
  if (blockIdx.y < (blockIdx.x & ~1u)) return;
  __shared__ float jx1[64], jy1[64], jx2[64], jy2[64], ja[64];
  int t = threadIdx.x;
  int jbase = blockIdx.y * 64;
  jx1[t] = sx1[jbase + t]; jy1[t] = sy1[jbase + t];
  jx2[t] = sx2[jbase + t]; jy2[t] = sy2[jbase + t];
  ja[t]  = sarea[jbase + t];
  __syncthreads();
  int i = blockIdx.x * 64 + t;
  float xi1 = sx1[i], yi1 = sy1[i], xi2 = sx2[i], yi2 = sy2[i], ai = sarea[i];
  u64 bits = 0ULL;
#pragma unroll 8
  for (int jj = 0; jj < 64; ++jj) {
    float xx1 = fmaxf(xi1, jx1[jj]);
    float yy1 = fmaxf(yi1, jy1[jj]);
    float xx2 = fminf(xi2, jx2[jj]);
    float yy2 = fminf(yi2, jy2[jj]);
    float w = fmaxf(xx2 - xx1, 0.0f);
    float h = fmaxf(yy2 - yy1, 0.0f);
    float inter = w * h;
    float den = ai + ja[jj] - inter;   // (ai + aj) - inter, numpy order
    float iou = inter / den;           // IEEE div; 0/0 -> NaN -> compare false
    if (iou > 0.5f) bits |= (1ULL << jj);
  }
  mask[(size_t)i * WROW + blockIdx.y] = bits;
  if ((blockIdx.y >> 1) == (blockIdx.x >> 1))
    diagI[((size_t)i << 1) + (blockIdx.y & 1)] = bits;
}

// ---------------------------------------------------------------------------
// Chunked greedy scan — R15 structure (dense phase-1: loads proven FREE,
// hidden behind the two barriers) with a shortened wave-0 serial segment:
//   - interleaved diag: (DA,AB) one b128 read; DB one read  (was 3 reads)
//   - sup pair (rem[2H],rem[2H+1]) one b128 read            (was 2 reads)
//   - keeps stores moved to wave 1 in phase 3 (off the critical segment)
// ---------------------------------------------------------------------------
__global__ __launch_bounds__(1024) void k_scan(
    const u64* __restrict__ mask,
    const u64* __restrict__ diagIg,
    unsigned int* __restrict__ cnt,
    unsigned int* __restrict__ keeps) {
  __shared__ __align__(16) u64 ldsDiag[2 * NCAP];   // 128 KB, interleaved
  __shared__ __align__(16) u64 rem[WROW];           // removed-set (1 KB)
  __shared__ u64 ldsKA, ldsKB;
  __shared__ int ldsKb;
  const int tid = threadIdx.x;
  const int F = (int)cnt[0];
  const int nch = (F + 127) >> 7;
  const ulonglong2* __restrict__ m2 = (const ulonglong2*)mask;  // 64 pairs/row

  for (int i = tid; i < 2 * NCAP; i += 1024) ldsDiag[i] = diagIg[i];
  for (int w = tid; w < WROW; w += 1024) rem[w] = 0;

  const int p0 = tid & 63;    // pair index (words 2p0, 2p0+1) of held rows
  const int g0 = tid >> 6;    // row group: rows g0 + 16k (k<8) of each chunk
  int K = 0;
  __syncthreads();            // staging + rem init visible

  for (int H = 0; H < nch; ++H) {
    const size_t gb = (size_t)H * 8192;   // chunk = 8192 linear 16B units
    const int base = H << 7;
    const bool ld = (p0 > H);             // both words >= 2H+2
    ulonglong2 v0 = {0,0}, v1 = {0,0}, v2 = {0,0}, v3 = {0,0},
               v4 = {0,0}, v5 = {0,0}, v6 = {0,0}, v7 = {0,0};
    if (ld) {
      v0 = m2[gb + tid];
      v1 = m2[gb + tid + 1024];
      v2 = m2[gb + tid + 2048];
      v3 = m2[gb + tid + 3072];
      v4 = m2[gb + tid + 4096];
      v5 = m2[gb + tid + 5120];
      v6 = m2[gb + tid + 6144];
      v7 = m2[gb + tid + 7168];
    }
    __syncthreads();   // prev chunk's rem ORs visible before greedy

    if (tid < 64) {
      // 3 LDS reads total (was 5): (DA,AB) b128, DB, (sup0,supB0) b128
      ulonglong2 dAB = *(const ulonglong2*)&ldsDiag[(size_t)(base + tid) << 1];
      u64 DA = dAB.x, AB = dAB.y;
      u64 DB = ldsDiag[(((size_t)(base + 64 + tid)) << 1) + 1];
      ulonglong2 supP = *(const ulonglong2*)&rem[2 * H];
      u64 sup0 = supP.x, supB0 = supP.y;

      int remrows = F - base;
      u64 validA = (remrows >= 64) ? ~0ull : ((1ull << remrows) - 1ull);
      int r2 = remrows - 64;
      u64 validB = (r2 >= 64) ? ~0ull : ((r2 <= 0) ? 0ull : ((1ull << r2) - 1ull));

      // ---- sub-greedy A (R10 involved-set shortcut) ----
      u64 DfwdA = (tid < 63) ? (DA & (~0ull << (tid + 1))) : 0ull;
      u64 undec = validA & ~sup0;
      u64 dmask = ((undec >> tid) & 1ull) ? DfwdA : 0ull;
      u64 vuln = wave_or64(dmask);
      u64 dang = __ballot(dmask != 0ull);
      u64 involved = (dang | vuln) & undec;
      u64 keepA = undec & ~involved;
      u64 und2 = involved;
      {
        unsigned Flo = (unsigned)DfwdA, Fhi = (unsigned)(DfwdA >> 32);
        while (und2) {
          int rr = __builtin_ctzll(und2);
          keepA |= 1ull << rr;
          unsigned dlo = __builtin_amdgcn_readlane(Flo, rr);
          unsigned dhi = __builtin_amdgcn_readlane(Fhi, rr);
          und2 &= ~((((u64)dhi << 32) | (u64)dlo) | (1ull << rr));
        }
      }

      // ---- A -> B suppression, then sub-greedy B ----
      u64 abm = ((keepA >> tid) & 1ull) ? AB : 0ull;
      u64 supB = supB0 | wave_or64(abm);
      u64 DfwdB = (tid < 63) ? (DB & (~0ull << (tid + 1))) : 0ull;
      u64 undecB = validB & ~supB;
      u64 dmaskB = ((undecB >> tid) & 1ull) ? DfwdB : 0ull;
      u64 vulnB = wave_or64(dmaskB);
      u64 dangB = __ballot(dmaskB != 0ull);
      u64 involvedB = (dangB | vulnB) & undecB;
      u64 keepB = undecB & ~involvedB;
      u64 und2B = involvedB;
      {
        unsigned Flo = (unsigned)DfwdB, Fhi = (unsigned)(DfwdB >> 32);
        while (und2B) {
          int rr = __builtin_ctzll(und2B);
          keepB |= 1ull << rr;
          unsigned dlo = __builtin_amdgcn_readlane(Flo, rr);
          unsigned dhi = __builtin_amdgcn_readlane(Fhi, rr);
          und2B &= ~((((u64)dhi << 32) | (u64)dlo) | (1ull << rr));
        }
      }

      if (tid == 0) { ldsKA = keepA; ldsKB = keepB; ldsKb = K; }
      K += __popcll(keepA) + __popcll(keepB);   // uniform; stores done by wave 1
    }
    __syncthreads();   // ldsKA/ldsKB/ldsKb visible

    const u64 keepA = ldsKA, keepB = ldsKB;

    // ---- keeps store by WAVE 1 (off wave-0's serial segment) ----
    if (g0 == 1) {
      const int l = p0;   // lane within wave 1
      const int Kb = ldsKb;
      int pcA = __popcll(keepA);
      unsigned kloA = (unsigned)keepA, khiA = (unsigned)(keepA >> 32);
      int preA = __builtin_amdgcn_mbcnt_hi(khiA, __builtin_amdgcn_mbcnt_lo(kloA, 0));
      if ((keepA >> l) & 1ull) keeps[Kb + preA] = (unsigned)(base + l);
      unsigned kloB = (unsigned)keepB, khiB = (unsigned)(keepB >> 32);
      int preB = __builtin_amdgcn_mbcnt_hi(khiB, __builtin_amdgcn_mbcnt_lo(kloB, 0));
      if ((keepB >> l) & 1ull) keeps[Kb + pcA + preB] = (unsigned)(base + 64 + l);
    }

    if (ld && (keepA | keepB)) {
      u64 ax = 0, ay = 0;                  // register pre-OR (R14)
      if ((keepA >> g0) & 1ull)        { ax |= v0.x; ay |= v0.y; }
      if ((keepA >> (g0+16)) & 1ull)   { ax |= v1.x; ay |= v1.y; }
      if ((keepA >> (g0+32)) & 1ull)   { ax |= v2.x; ay |= v2.y; }
      if ((keepA >> (g0+48)) & 1ull)   { ax |= v3.x; ay |= v3.y; }
      if ((keepB >> g0) & 1ull)        { ax |= v4.x; ay |= v4.y; }
      if ((keepB >> (g0+16)) & 1ull)   { ax |= v5.x; ay |= v5.y; }
      if ((keepB >> (g0+32)) & 1ull)   { ax |= v6.x; ay |= v6.y; }
      if ((keepB >> (g0+48)) & 1ull)   { ax |= v7.x; ay |= v7.y; }
      const int w0 = 2 * p0;
      if (ax) atomicOr(&rem[w0], ax);
      if (ay) atomicOr(&rem[w0 + 1], ay);
    }
    // next iteration's first barrier orders these ORs before rem reads
  }
  if (tid == 0) cnt[1] = (unsigned int)K;
}

// Fallback (small workspace): on-the-fly IoU greedy scan in one block.
__global__ __launch_bounds__(256) void k_scan_nomask(
    const float* __restrict__ sx1, const float* __restrict__ sy1,
    const float* __restrict__ sx2, const float* __restrict__ sy2,
    const float* __restrict__ sarea,
    unsigned int* __restrict__ cnt,
    unsigned int* __restrict__ keeps) {
  __shared__ unsigned char sup[NCAP];
  __shared__ int sK;
  int tid = threadIdx.x;
  int F = (int)cnt[0];
  for (int j = tid; j < NCAP; j += 256) sup[j] = 0;
  if (tid == 0) sK = 0;
  __syncthreads();
  for (int i = 0; i < F; ++i) {
    if (!sup[i]) {
      if (tid == 0) keeps[sK++] = (unsigned int)i;
      float xi1 = sx1[i], yi1 = sy1[i], xi2 = sx2[i], yi2 = sy2[i], ai = sarea[i];
      for (int j = i + 1 + tid; j < F; j += 256) {
        if (sup[j]) continue;
        float xx1 = fmaxf(xi1, sx1[j]);
        float yy1 = fmaxf(yi1, sy1[j]);
        float xx2 = fminf(xi2, sx2[j]);
        float yy2 = fminf(yi2, sy2[j]);
        float w = fmaxf(xx2 - xx1, 0.0f);
        float h = fmaxf(yy2 - yy1, 0.0f);
        float inter = w * h;
        float iou = inter / (ai + sarea[j] - inter);
        if (iou > 0.5f) sup[j] = 1;
      }
    }
    __syncthreads();
  }
  if (tid == 0) cnt[1] = (unsigned int)sK;
}

// ---------------------------------------------------------------------------
// Per class: top-KT over M kept boxes, REGISTER-RESIDENT (R13, unchanged).
// ---------------------------------------------------------------------------
__global__ __launch_bounds__(1024) void k_topk(
    const float* __restrict__ conf,
    const unsigned int* __restrict__ sorig,
    const unsigned int* __restrict__ keeps,
    const unsigned int* __restrict__ cnt,
    int C, int KT,
    float* __restrict__ topv, int* __restrict__ topi) {
  __shared__ float wlv[16];
  __shared__ int wli[16];
  __shared__ float ldsWv;
  __shared__ int ldsWj;
  const int tid = threadIdx.x;
  const int lane = tid & 63;
  const int wv_ = tid >> 6;
  const int c = blockIdx.x;
  const int M = (int)cnt[1];

  const float NEG = -3.402823466e+38f;
  float v[8];
#pragma unroll
  for (int k = 0; k < 8; ++k) {
    int j = tid + (k << 10);
    v[k] = (j < M) ? conf[(size_t)sorig[keeps[j]] * C + c] : NEG;
  }
  // thread-local argmax (global index tie-break: smaller k first is smaller j)
  float bv = NEG; int bk_ = -1;
#pragma unroll
  for (int k = 0; k < 8; ++k)
    if (v[k] > bv) { bv = v[k]; bk_ = k; }
  int bj = (bk_ >= 0) ? (tid + (bk_ << 10)) : 0x7FFFFFFF;
  if (bv == NEG) bj = 0x7FFFFFFF;

  for (int t = 0; t < KT; ++t) {
    // wave reduce
    float rv = bv; int rj = bj;
#pragma unroll
    for (int off = 32; off; off >>= 1) {
      float v2 = __shfl_down(rv, off);
      int   j2 = __shfl_down(rj, off);
      if (v2 > rv || (v2 == rv && j2 < rj)) { rv = v2; rj = j2; }
    }
    if (lane == 0) { wlv[wv_] = rv; wli[wv_] = rj; }
    __syncthreads();
    if (wv_ == 0) {
      float fv = (lane < 16) ? wlv[lane] : NEG;
      int   fj = (lane < 16) ? wli[lane] : 0x7FFFFFFF;
#pragma unroll
      for (int off = 32; off; off >>= 1) {
        float v2 = __shfl_down(fv, off);
        int   j2 = __shfl_down(fj, off);
        if (v2 > fv || (v2 == fv && j2 < fj)) { fv = v2; fj = j2; }
      }
      if (lane == 0) {
        ldsWv = fv; ldsWj = fj;
        topv[c * KT + t] = fv;
        topi[c * KT + t] = (fj == 0x7FFFFFFF) ? 0 : fj;  // M<KT safety
      }
    }
    __syncthreads();
    const int wj = ldsWj;
    if (wj != 0x7FFFFFFF && (wj & 1023) == tid) {
      int kk = wj >> 10;
#pragma unroll
      for (int k = 0; k < 8; ++k)
        if (k == kk) v[k] = NEG;
      bv = NEG; bk_ = -1;
#pragma unroll
      for (int k = 0; k < 8; ++k)
        if (v[k] > bv) { bv = v[k]; bk_ = k; }
      bj = (bk_ >= 0) ? (tid + (bk_ << 10)) : 0x7FFFFFFF;
      if (bv == NEG) bj = 0x7FFFFFFF;
    }
  }
}

// Final scalar: smooth-L1 over (KT, C, 4) gathered boxes + focal CE on
// (class0 top-KT > 0.5), divided by M.
__global__ __launch_bounds__(256) void k_loss(
    const float* __restrict__ loc, const float* __restrict__ tb,
    const int* __restrict__ labels,
    const unsigned int* __restrict__ sorig,
    const unsigned int* __restrict__ keeps,
    const float* __restrict__ topv, const int* __restrict__ topi,
    const unsigned int* __restrict__ cnt, int C, int KT,
    float* __restrict__ out) {
  __shared__ float red[256];
  int tid = threadIdx.x;
  int F = (int)cnt[0];
  int M = (int)cnt[1];
  if (F == 0 || M == 0) {
    if (tid == 0) out[0] = 0.001f;
    return;
  }
  int total = KT * C * 4;
  float part = 0.0f;
  for (int e = tid; e < total; e += 256) {
    int d = e & 3;
    int q = e >> 2;
    int c = q % C;
    int i = q / C;
    int j = topi[c * KT + i];
    unsigned int orow = sorig[keeps[j]];
    float pred = loc[(size_t)orow * 4 + d];
    float tg = tb[c * 4 + d];
    float dd = fabsf(pred - tg);
    part += (dd < 1.0f) ? (0.5f * dd * dd) : (dd - 0.5f);
  }
  red[tid] = part;
  __syncthreads();
  for (int s = 128; s > 0; s >>= 1) {
    if (tid < s) red[tid] += red[tid + s];
    __syncthreads();
  }
  if (tid == 0) {
    float loc_loss = red[0];
    float mx = -3.402823466e+38f;
    for (int i = 0; i < KT; ++i) {
      float x = (topv[i] > 0.5f) ? 1.0f : 0.0f;   // class 0 column
      mx = fmaxf(mx, x);
    }
    float ssum = 0.0f;
    for (int i = 0; i < KT; ++i) {
      float x = (topv[i] > 0.5f) ? 1.0f : 0.0f;
      ssum += expf(x - mx);
    }
    float lse = mx + logf(ssum);
    float ce = 0.0f;
    for (int i = 0; i < KT; ++i) {
      float x = (topv[i] > 0.5f) ? 1.0f : 0.0f;
      ce += (float)labels[i] * (x - lse);
    }
    ce = -ce;
    float pt = expf(-ce);
    float om = 1.0f - pt;
    float conf_loss = 0.25f * om * om * ce;   // ALPHA=0.25, GAMMA=2
    out[0] = (loc_loss + conf_loss) / (float)M;
  }
}

// ---------------- host ------------------------------------------------------

extern "C" void kernel_launch(void* const* d_in, const int* in_sizes, int n_in,
                              void* d_out, int out_size, void* d_ws, size_t ws_size,
                              hipStream_t stream) {
  (void)n_in; (void)out_size;
  const float* loc    = (const float*)d_in[0];
  const float* conf   = (const float*)d_in[1];
  const float* tb     = (const float*)d_in[2];
  const int*   labels = (const int*)d_in[3];
  float* out = (float*)d_out;

  int N = in_sizes[0] / 4;
  if (N > NCAP) N = NCAP;
  int C  = (N > 0) ? (in_sizes[1] / N) : 20;
  int KT = in_sizes[3];

  char* ws = (char*)d_ws;
  unsigned int* cnt   = (unsigned int*)(ws + OFF_CNT);
  float*        sx1   = (float*)(ws + OFF_SX1);
  float*        sy1   = (float*)(ws + OFF_SY1);
  float*        sx2   = (float*)(ws + OFF_SX2);
  float*        sy2   = (float*)(ws + OFF_SY2);
  float*        sarea = (float*)(ws + OFF_AREA);
  unsigned int* sorig = (unsigned int*)(ws + OFF_SORIG);
  unsigned int* keeps = (unsigned int*)(ws + OFF_KEEPS);
  float*        topv  = (float*)(ws + OFF_TOPV);
  int*          topi  = (int*)(ws + OFF_TOPI);
  u64*          diagI = (u64*)(ws + OFF_DIAG2);
  u64*          mask  = (u64*)(ws + OFF_MASK);

  bool use_mask = (ws_size >= WS_NEED_MASK);

  k_sortf<<<1, 1024, 0, stream>>>(conf, loc, N, C, cnt,
                                  sx1, sy1, sx2, sy2, sarea, sorig);
  if (use_mask) {
    k_mask<<<dim3(WROW, WROW), 64, 0, stream>>>(sx1, sy1, sx2, sy2, sarea,
                                                mask, diagI);
    k_scan<<<1, 1024, 0, stream>>>(mask, diagI, cnt, keeps);
  } else {
    k_scan_nomask<<<1, 256, 0, stream>>>(sx1, sy1, sx2, sy2, sarea, cnt, keeps);
  }
  k_topk<<<C, 1024, 0, stream>>>(conf, sorig, keeps, cnt, C, KT, topv, topi);
  k_loss<<<1, 256, 0, stream>>>(loc, tb, labels, sorig, keeps, topv, topi, cnt, C, KT, out);
}

// Round 18
// 339.696 us; speedup vs baseline: 1.1279x; 1.1061x over previous
//
#include <hip/hip_runtime.h>
#include <stdint.h>
#include <stddef.h>

// ---------------------------------------------------------------------------
// BoundingBox loss processor:
//   filter (maxconf > 0.6) -> sort by class-0 score desc (stable, idx asc)
//   -> greedy NMS (IoU > 0.5 suppress) -> per-class top-20 over kept
//   -> smooth-L1 sum + focal CE on (class0 top-20 > 0.5) -> /M
//
// Journal: R10 involved-set greedy. R13 register topk. R14 pre-OR atomics.
// R15 128-row chunks. R17 short wave-0 segment: k_scan 136us, total 376.
// R18: sort split — k_psort (16 blocks) runs the wave-local phases bk<=512
// of the bitonic network in parallel (45 of 91 steps + key build); k_merge
// (1 block) runs only merge phases bk>=1024 + gather epilogue. Exact same
// comparator network on unique keys -> identical order.
// ---------------------------------------------------------------------------

#define NCAP 8192
#define WROW (NCAP / 64)   // 128 u64 words per mask row

typedef unsigned long long u64;

// ---------------- workspace layout (all offsets 16-byte aligned) -----------
constexpr size_t OFF_CNT   = 0;                               // 2 x u32: [0]=F, [1]=M
constexpr size_t OFF_KEYS  = 256;                             // u64[NCAP] (psort->merge)
constexpr size_t OFF_SX1   = OFF_KEYS + 8ull * NCAP;          // f32[NCAP]
constexpr size_t OFF_SY1   = OFF_SX1 + 4ull * NCAP;
constexpr size_t OFF_SX2   = OFF_SY1 + 4ull * NCAP;
constexpr size_t OFF_SY2   = OFF_SX2 + 4ull * NCAP;
constexpr size_t OFF_AREA  = OFF_SY2 + 4ull * NCAP;
constexpr size_t OFF_SORIG = OFF_AREA + 4ull * NCAP;          // u32[NCAP]
constexpr size_t OFF_KEEPS = OFF_SORIG + 4ull * NCAP;         // u32[NCAP]
constexpr size_t OFF_KORIG = OFF_KEEPS + 4ull * NCAP;         // u32[NCAP] (unused)
constexpr size_t OFF_TOPV  = OFF_KORIG + 4ull * NCAP;         // f32[1024]
constexpr size_t OFF_TOPI  = OFF_TOPV + 4096;                 // i32[1024]
constexpr size_t OFF_DIAG2 = OFF_TOPI + 4096;                 // u64[2*NCAP] = 128 KB, interleaved
constexpr size_t OFF_MASK  = OFF_DIAG2 + 16ull * NCAP;        // u64[NCAP*WROW] = 8 MB
constexpr size_t WS_NEED_MASK = OFF_MASK + 8ull * NCAP * WROW;

// wave-wide OR of a u64 (6 butterfly steps, 2x32b shuffles each)
__device__ __forceinline__ u64 wave_or64(u64 x) {
#pragma unroll
  for (int off = 1; off < 64; off <<= 1) {
    unsigned lo = __shfl_xor((unsigned)x, off);
    unsigned hi = __shfl_xor((unsigned)(x >> 32), off);
    x |= ((u64)hi << 32) | lo;
  }
  return x;
}

// ---------------- bitonic building blocks (shared by k_psort / k_merge) ----
#define SS1(M)                                                              \
  { int tt = base + (M) * 64 + l;                                           \
    u64 a = e[M];                                                           \
    unsigned slo = __shfl_xor((unsigned)a, (int)jj);                        \
    unsigned shi = __shfl_xor((unsigned)(a >> 32), (int)jj);                \
    u64 b = ((u64)shi << 32) | slo;                                         \
    bool up = ((tt & bk) == 0);                                             \
    bool lowr = ((l & (int)jj) == 0);                                       \
    bool tmin = (up == lowr);                                               \
    bool agtb = (a > b);                                                    \
    e[M] = (tmin == agtb) ? b : a; }

#define SSTEP() { SS1(0) SS1(1) SS1(2) SS1(3) SS1(4) SS1(5) SS1(6) SS1(7) }

#define CSW(A, B)                                                           \
  { int tt = base + (A) * 64 + l;                                           \
    bool up = ((tt & bk) == 0);                                             \
    u64 xa = e[A], xb = e[B];                                               \
    bool sw = up ? (xa > xb) : (xa < xb);                                   \
    e[A] = sw ? xb : xa; e[B] = sw ? xa : xb; }

#define RSTEP4() { CSW(0,4) CSW(1,5) CSW(2,6) CSW(3,7) }
#define RSTEP2() { CSW(0,2) CSW(1,3) CSW(4,6) CSW(5,7) }
#define RSTEP1() { CSW(0,1) CSW(2,3) CSW(4,5) CSW(6,7) }

// ---------------------------------------------------------------------------
// Parallel pre-sort: 16 blocks x 1 wave; block b builds keys for rows
// [512b, 512b+512) and runs bitonic phases bk=2..512 (wave-local: partner
// indices differ only in bits < 512). Comparator direction uses the GLOBAL
// index -> exact prefix of the full network (alternating block directions
// ready for the bk=1024 merge phase).
// ---------------------------------------------------------------------------
__global__ __launch_bounds__(64) void k_psort(
    const float* __restrict__ conf, int N, int C,
    u64* __restrict__ keys) {
  const int l = threadIdx.x;
  const int base = blockIdx.x * 512;
  u64 e[8];
#pragma unroll
  for (int m = 0; m < 8; ++m) {
    int row = base + m * 64 + l;
    u64 key;
    if (row < N) {
      const float* cr = conf + (size_t)row * C;
      float mx = cr[0];
      for (int c = 1; c < C; ++c) mx = fmaxf(mx, cr[c]);
      unsigned int k32;
      if (mx > 0.6f) {
        union { float f; unsigned int u; } s; s.f = cr[0];
        unsigned int u = s.u;
        u = (u & 0x80000000u) ? ~u : (u | 0x80000000u);  // monotone map
        k32 = ~u;                                        // descending
        if (k32 == 0xFFFFFFFFu) k32 = 0xFFFFFFFEu;       // reserve invalid
      } else {
        k32 = 0xFFFFFFFFu;
      }
      key = ((u64)k32 << 32) | (unsigned int)row;
    } else {
      key = ((u64)0xFFFFFFFFu << 32);
    }
    e[m] = key;
  }
  for (unsigned bk = 2; bk <= 512; bk <<= 1) {
    unsigned j = bk >> 1;
    if (j == 256) { RSTEP4(); j = 128; }
    if (j == 128) { RSTEP2(); j = 64; }
    if (j == 64)  { RSTEP1(); j = 32; }
    for (unsigned jj = j; jj >= 1; jj >>= 1) SSTEP();
  }
#pragma unroll
  for (int m = 0; m < 8; ++m) keys[base + m * 64 + l] = e[m];
}

// ---------------------------------------------------------------------------
// Merge phases bk=1024..8192 (one block) + count/gather epilogue.
// ---------------------------------------------------------------------------
__global__ __launch_bounds__(1024) void k_merge(
    const float* __restrict__ loc,
    u64* __restrict__ keys, unsigned int* __restrict__ cnt,
    float* __restrict__ sx1, float* __restrict__ sy1,
    float* __restrict__ sx2, float* __restrict__ sy2,
    float* __restrict__ sarea, unsigned int* __restrict__ sorig) {
  __shared__ u64 sk[NCAP];  // 64 KiB (j>=512 sessions)
  __shared__ int wsum[16];
  const int tid = threadIdx.x;
  const int w = tid >> 6, l = tid & 63;
  const int base = w * 512;
  u64 e[8];
#pragma unroll
  for (int m = 0; m < 8; ++m) e[m] = keys[base + m * 64 + l];

  for (unsigned bk = 1024; bk <= NCAP; bk <<= 1) {
    unsigned j = bk >> 1;   // >= 512 always
    {
#pragma unroll
      for (int m = 0; m < 8; ++m) sk[base + m * 64 + l] = e[m];
      __syncthreads();
      for (unsigned j2 = bk >> 1; j2 >= 512; j2 >>= 1) {
        for (int tl = tid; tl < NCAP; tl += 1024) {
          unsigned p = (unsigned)tl ^ j2;
          if (p > (unsigned)tl) {
            bool up = ((tl & bk) == 0);
            u64 x = sk[tl], y = sk[p];
            bool sw = up ? (x > y) : (x < y);
            if (sw) { sk[tl] = y; sk[p] = x; }
          }
        }
        __syncthreads();
      }
#pragma unroll
      for (int m = 0; m < 8; ++m) e[m] = sk[base + m * 64 + l];
      __syncthreads();   // protect sk reads from next session's writes
      j = 256;
    }
    if (j == 256) { RSTEP4(); j = 128; }
    if (j == 128) { RSTEP2(); j = 64; }
    if (j == 64)  { RSTEP1(); j = 32; }
    for (unsigned jj = j; jj >= 1; jj >>= 1) SSTEP();
  }

  // epilogue: count valid + fused gather
  int cv = 0;
#pragma unroll
  for (int m = 0; m < 8; ++m) {
    int idx = base + m * 64 + l;
    u64 key = e[m];
    if ((key >> 32) != 0xFFFFFFFFull) ++cv;
    unsigned row = (unsigned)(key & 0xFFFFFFFFull);
    const float* b = loc + (size_t)row * 4;
    float x1 = b[0], y1 = b[1], x2 = b[2], y2 = b[3];
    sx1[idx] = x1; sy1[idx] = y1; sx2[idx] = x2; sy2[idx] = y2;
    sarea[idx] = (x2 - x1) * (y2 - y1);   // numpy op order, no FMA hazard
    sorig[idx] = row;
  }
  for (int off = 32; off; off >>= 1) cv += __shfl_down(cv, off);
  if (l == 0) wsum[w] = cv;
  __syncthreads();
  if (tid == 0) {
    int s = 0;
    for (int i = 0; i < 16; ++i) s += wsum[i];
    cnt[0] = (unsigned int)s;
  }
}

// Pairwise IoU>0.5 bitmask, 64x64 tiles, 1 wave per block.
// Skip by < (bx & ~1) (never consumed). Diagonal-super blocks write the
// INTERLEAVED diag strip: diagI[2*i + (by&1)].
__global__ __launch_bounds__(64) void k_mask(
    const float* __restrict__ sx1, const float* __restrict__ sy1,
    const float* __restrict__ sx2, const float* __restrict__ sy2,
    const float* __restrict__ sarea,
    u64* __restrict__ mask, u64* __restrict__ diagI) {
  if (blockIdx.y < (blockIdx.x & ~1u)) return;
  __shared__ float jx1[64], jy1[64], jx2[64], jy2[64], ja[64];
  int t = threadIdx.x;
  int jbase = blockIdx.y * 64;
  jx1[t] = sx1[jbase + t]; jy1[t] = sy1[jbase + t];
  jx2[t] = sx2[jbase + t]; jy2[t] = sy2[jbase + t];
  ja[t]  = sarea[jbase + t];
  __syncthreads();
  int i = blockIdx.x * 64 + t;
  float xi1 = sx1[i], yi1 = sy1[i], xi2 = sx2[i], yi2 = sy2[i], ai = sarea[i];
  u64 bits = 0ULL;
#pragma unroll 8
  for (int jj = 0; jj < 64; ++jj) {
    float xx1 = fmaxf(xi1, jx1[jj]);
    float yy1 = fmaxf(yi1, jy1[jj]);
    float xx2 = fminf(xi2, jx2[jj]);
    float yy2 = fminf(yi2, jy2[jj]);
    float w = fmaxf(xx2 - xx1, 0.0f);
    float h = fmaxf(yy2 - yy1, 0.0f);
    float inter = w * h;
    float den = ai + ja[jj] - inter;   // (ai + aj) - inter, numpy order
    float iou = inter / den;           // IEEE div; 0/0 -> NaN -> compare false
    if (iou > 0.5f) bits |= (1ULL << jj);
  }
  mask[(size_t)i * WROW + blockIdx.y] = bits;
  if ((blockIdx.y >> 1) == (blockIdx.x >> 1))
    diagI[((size_t)i << 1) + (blockIdx.y & 1)] = bits;
}

// ---------------------------------------------------------------------------
// Chunked greedy scan — R17 version VERBATIM (136 us; do not perturb).
// ---------------------------------------------------------------------------
__global__ __launch_bounds__(1024) void k_scan(
    const u64* __restrict__ mask,
    const u64* __restrict__ diagIg,
    unsigned int* __restrict__ cnt,
    unsigned int* __restrict__ keeps) {
  __shared__ __align__(16) u64 ldsDiag[2 * NCAP];   // 128 KB, interleaved
  __shared__ __align__(16) u64 rem[WROW];           // removed-set (1 KB)
  __shared__ u64 ldsKA, ldsKB;
  __shared__ int ldsKb;
  const int tid = threadIdx.x;
  const int F = (int)cnt[0];
  const int nch = (F + 127) >> 7;
  const ulonglong2* __restrict__ m2 = (const ulonglong2*)mask;  // 64 pairs/row

  for (int i = tid; i < 2 * NCAP; i += 1024) ldsDiag[i] = diagIg[i];
  for (int w = tid; w < WROW; w += 1024) rem[w] = 0;

  const int p0 = tid & 63;    // pair index (words 2p0, 2p0+1) of held rows
  const int g0 = tid >> 6;    // row group: rows g0 + 16k (k<8) of each chunk
  int K = 0;
  __syncthreads();            // staging + rem init visible

  for (int H = 0; H < nch; ++H) {
    const size_t gb = (size_t)H * 8192;   // chunk = 8192 linear 16B units
    const int base = H << 7;
    const bool ld = (p0 > H);             // both words >= 2H+2
    ulonglong2 v0 = {0,0}, v1 = {0,0}, v2 = {0,0}, v3 = {0,0},
               v4 = {0,0}, v5 = {0,0}, v6 = {0,0}, v7 = {0,0};
    if (ld) {
      v0 = m2[gb + tid];
      v1 = m2[gb + tid + 1024];
      v2 = m2[gb + tid + 2048];
      v3 = m2[gb + tid + 3072];
      v4 = m2[gb + tid + 4096];
      v5 = m2[gb + tid + 5120];
      v6 = m2[gb + tid + 6144];
      v7 = m2[gb + tid + 7168];
    }
    __syncthreads();   // prev chunk's rem ORs visible before greedy

    if (tid < 64) {
      // 3 LDS reads total: (DA,AB) b128, DB, (sup0,supB0) b128
      ulonglong2 dAB = *(const ulonglong2*)&ldsDiag[(size_t)(base + tid) << 1];
      u64 DA = dAB.x, AB = dAB.y;
      u64 DB = ldsDiag[(((size_t)(base + 64 + tid)) << 1) + 1];
      ulonglong2 supP = *(const ulonglong2*)&rem[2 * H];
      u64 sup0 = supP.x, supB0 = supP.y;

      int remrows = F - base;
      u64 validA = (remrows >= 64) ? ~0ull : ((1ull << remrows) - 1ull);
      int r2 = remrows - 64;
      u64 validB = (r2 >= 64) ? ~0ull : ((r2 <= 0) ? 0ull : ((1ull << r2) - 1ull));

      // ---- sub-greedy A (R10 involved-set shortcut) ----
      u64 DfwdA = (tid < 63) ? (DA & (~0ull << (tid + 1))) : 0ull;
      u64 undec = validA & ~sup0;
      u64 dmask = ((undec >> tid) & 1ull) ? DfwdA : 0ull;
      u64 vuln = wave_or64(dmask);
      u64 dang = __ballot(dmask != 0ull);
      u64 involved = (dang | vuln) & undec;
      u64 keepA = undec & ~involved;
      u64 und2 = involved;
      {
        unsigned Flo = (unsigned)DfwdA, Fhi = (unsigned)(DfwdA >> 32);
        while (und2) {
          int rr = __builtin_ctzll(und2);
          keepA |= 1ull << rr;
          unsigned dlo = __builtin_amdgcn_readlane(Flo, rr);
          unsigned dhi = __builtin_amdgcn_readlane(Fhi, rr);
          und2 &= ~((((u64)dhi << 32) | (u64)dlo) | (1ull << rr));
        }
      }

      // ---- A -> B suppression, then sub-greedy B ----
      u64 abm = ((keepA >> tid) & 1ull) ? AB : 0ull;
      u64 supB = supB0 | wave_or64(abm);
      u64 DfwdB = (tid < 63) ? (DB & (~0ull << (tid + 1))) : 0ull;
      u64 undecB = validB & ~supB;
      u64 dmaskB = ((undecB >> tid) & 1ull) ? DfwdB : 0ull;
      u64 vulnB = wave_or64(dmaskB);
      u64 dangB = __ballot(dmaskB != 0ull);
      u64 involvedB = (dangB | vulnB) & undecB;
      u64 keepB = undecB & ~involvedB;
      u64 und2B = involvedB;
      {
        unsigned Flo = (unsigned)DfwdB, Fhi = (unsigned)(DfwdB >> 32);
        while (und2B) {
          int rr = __builtin_ctzll(und2B);
          keepB |= 1ull << rr;
          unsigned dlo = __builtin_amdgcn_readlane(Flo, rr);
          unsigned dhi = __builtin_amdgcn_readlane(Fhi, rr);
          und2B &= ~((((u64)dhi << 32) | (u64)dlo) | (1ull << rr));
        }
      }

      if (tid == 0) { ldsKA = keepA; ldsKB = keepB; ldsKb = K; }
      K += __popcll(keepA) + __popcll(keepB);   // uniform; stores by wave 1
    }
    __syncthreads();   // ldsKA/ldsKB/ldsKb visible

    const u64 keepA = ldsKA, keepB = ldsKB;

    // ---- keeps store by WAVE 1 (off wave-0's serial segment) ----
    if (g0 == 1) {
      const int l = p0;
      const int Kb = ldsKb;
      int pcA = __popcll(keepA);
      unsigned kloA = (unsigned)keepA, khiA = (unsigned)(keepA >> 32);
      int preA = __builtin_amdgcn_mbcnt_hi(khiA, __builtin_amdgcn_mbcnt_lo(kloA, 0));
      if ((keepA >> l) & 1ull) keeps[Kb + preA] = (unsigned)(base + l);
      unsigned kloB = (unsigned)keepB, khiB = (unsigned)(keepB >> 32);
      int preB = __builtin_amdgcn_mbcnt_hi(khiB, __builtin_amdgcn_mbcnt_lo(kloB, 0));
      if ((keepB >> l) & 1ull) keeps[Kb + pcA + preB] = (unsigned)(base + 64 + l);
    }

    if (ld && (keepA | keepB)) {
      u64 ax = 0, ay = 0;                  // register pre-OR (R14)
      if ((keepA >> g0) & 1ull)        { ax |= v0.x; ay |= v0.y; }
      if ((keepA >> (g0+16)) & 1ull)   { ax |= v1.x; ay |= v1.y; }
      if ((keepA >> (g0+32)) & 1ull)   { ax |= v2.x; ay |= v2.y; }
      if ((keepA >> (g0+48)) & 1ull)   { ax |= v3.x; ay |= v3.y; }
      if ((keepB >> g0) & 1ull)        { ax |= v4.x; ay |= v4.y; }
      if ((keepB >> (g0+16)) & 1ull)   { ax |= v5.x; ay |= v5.y; }
      if ((keepB >> (g0+32)) & 1ull)   { ax |= v6.x; ay |= v6.y; }
      if ((keepB >> (g0+48)) & 1ull)   { ax |= v7.x; ay |= v7.y; }
      const int w0 = 2 * p0;
      if (ax) atomicOr(&rem[w0], ax);
      if (ay) atomicOr(&rem[w0 + 1], ay);
    }
    // next iteration's first barrier orders these ORs before rem reads
  }
  if (tid == 0) cnt[1] = (unsigned int)K;
}

// Fallback (small workspace): on-the-fly IoU greedy scan in one block.
__global__ __launch_bounds__(256) void k_scan_nomask(
    const float* __restrict__ sx1, const float* __restrict__ sy1,
    const float* __restrict__ sx2, const float* __restrict__ sy2,
    const float* __restrict__ sarea,
    unsigned int* __restrict__ cnt,
    unsigned int* __restrict__ keeps) {
  __shared__ unsigned char sup[NCAP];
  __shared__ int sK;
  int tid = threadIdx.x;
  int F = (int)cnt[0];
  for (int j = tid; j < NCAP; j += 256) sup[j] = 0;
  if (tid == 0) sK = 0;
  __syncthreads();
  for (int i = 0; i < F; ++i) {
    if (!sup[i]) {
      if (tid == 0) keeps[sK++] = (unsigned int)i;
      float xi1 = sx1[i], yi1 = sy1[i], xi2 = sx2[i], yi2 = sy2[i], ai = sarea[i];
      for (int j = i + 1 + tid; j < F; j += 256) {
        if (sup[j]) continue;
        float xx1 = fmaxf(xi1, sx1[j]);
        float yy1 = fmaxf(yi1, sy1[j]);
        float xx2 = fminf(xi2, sx2[j]);
        float yy2 = fminf(yi2, sy2[j]);
        float w = fmaxf(xx2 - xx1, 0.0f);
        float h = fmaxf(yy2 - yy1, 0.0f);
        float inter = w * h;
        float iou = inter / (ai + sarea[j] - inter);
        if (iou > 0.5f) sup[j] = 1;
      }
    }
    __syncthreads();
  }
  if (tid == 0) cnt[1] = (unsigned int)sK;
}

// ---------------------------------------------------------------------------
// Per class: top-KT over M kept boxes, REGISTER-RESIDENT (R13, unchanged).
// ---------------------------------------------------------------------------
__global__ __launch_bounds__(1024) void k_topk(
    const float* __restrict__ conf,
    const unsigned int* __restrict__ sorig,
    const unsigned int* __restrict__ keeps,
    const unsigned int* __restrict__ cnt,
    int C, int KT,
    float* __restrict__ topv, int* __restrict__ topi) {
  __shared__ float wlv[16];
  __shared__ int wli[16];
  __shared__ float ldsWv;
  __shared__ int ldsWj;
  const int tid = threadIdx.x;
  const int lane = tid & 63;
  const int wv_ = tid >> 6;
  const int c = blockIdx.x;
  const int M = (int)cnt[1];

  const float NEG = -3.402823466e+38f;
  float v[8];
#pragma unroll
  for (int k = 0; k < 8; ++k) {
    int j = tid + (k << 10);
    v[k] = (j < M) ? conf[(size_t)sorig[keeps[j]] * C + c] : NEG;
  }
  float bv = NEG; int bk_ = -1;
#pragma unroll
  for (int k = 0; k < 8; ++k)
    if (v[k] > bv) { bv = v[k]; bk_ = k; }
  int bj = (bk_ >= 0) ? (tid + (bk_ << 10)) : 0x7FFFFFFF;
  if (bv == NEG) bj = 0x7FFFFFFF;

  for (int t = 0; t < KT; ++t) {
    float rv = bv; int rj = bj;
#pragma unroll
    for (int off = 32; off; off >>= 1) {
      float v2 = __shfl_down(rv, off);
      int   j2 = __shfl_down(rj, off);
      if (v2 > rv || (v2 == rv && j2 < rj)) { rv = v2; rj = j2; }
    }
    if (lane == 0) { wlv[wv_] = rv; wli[wv_] = rj; }
    __syncthreads();
    if (wv_ == 0) {
      float fv = (lane < 16) ? wlv[lane] : NEG;
      int   fj = (lane < 16) ? wli[lane] : 0x7FFFFFFF;
#pragma unroll
      for (int off = 32; off; off >>= 1) {
        float v2 = __shfl_down(fv, off);
        int   j2 = __shfl_down(fj, off);
        if (v2 > fv || (v2 == fv && j2 < fj)) { fv = v2; fj = j2; }
      }
      if (lane == 0) {
        ldsWv = fv; ldsWj = fj;
        topv[c * KT + t] = fv;
        topi[c * KT + t] = (fj == 0x7FFFFFFF) ? 0 : fj;  // M<KT safety
      }
    }
    __syncthreads();
    const int wj = ldsWj;
    if (wj != 0x7FFFFFFF && (wj & 1023) == tid) {
      int kk = wj >> 10;
#pragma unroll
      for (int k = 0; k < 8; ++k)
        if (k == kk) v[k] = NEG;
      bv = NEG; bk_ = -1;
#pragma unroll
      for (int k = 0; k < 8; ++k)
        if (v[k] > bv) { bv = v[k]; bk_ = k; }
      bj = (bk_ >= 0) ? (tid + (bk_ << 10)) : 0x7FFFFFFF;
      if (bv == NEG) bj = 0x7FFFFFFF;
    }
  }
}

// Final scalar: smooth-L1 over (KT, C, 4) gathered boxes + focal CE on
// (class0 top-KT > 0.5), divided by M.
__global__ __launch_bounds__(256) void k_loss(
    const float* __restrict__ loc, const float* __restrict__ tb,
    const int* __restrict__ labels,
    const unsigned int* __restrict__ sorig,
    const unsigned int* __restrict__ keeps,
    const float* __restrict__ topv, const int* __restrict__ topi,
    const unsigned int* __restrict__ cnt, int C, int KT,
    float* __restrict__ out) {
  __shared__ float red[256];
  int tid = threadIdx.x;
  int F = (int)cnt[0];
  int M = (int)cnt[1];
  if (F == 0 || M == 0) {
    if (tid == 0) out[0] = 0.001f;
    return;
  }
  int total = KT * C * 4;
  float part = 0.0f;
  for (int e = tid; e < total; e += 256) {
    int d = e & 3;
    int q = e >> 2;
    int c = q % C;
    int i = q / C;
    int j = topi[c * KT + i];
    unsigned int orow = sorig[keeps[j]];
    float pred = loc[(size_t)orow * 4 + d];
    float tg = tb[c * 4 + d];
    float dd = fabsf(pred - tg);
    part += (dd < 1.0f) ? (0.5f * dd * dd) : (dd - 0.5f);
  }
  red[tid] = part;
  __syncthreads();
  for (int s = 128; s > 0; s >>= 1) {
    if (tid < s) red[tid] += red[tid + s];
    __syncthreads();
  }
  if (tid == 0) {
    float loc_loss = red[0];
    float mx = -3.402823466e+38f;
    for (int i = 0; i < KT; ++i) {
      float x = (topv[i] > 0.5f) ? 1.0f : 0.0f;   // class 0 column
      mx = fmaxf(mx, x);
    }
    float ssum = 0.0f;
    for (int i = 0; i < KT; ++i) {
      float x = (topv[i] > 0.5f) ? 1.0f : 0.0f;
      ssum += expf(x - mx);
    }
    float lse = mx + logf(ssum);
    float ce = 0.0f;
    for (int i = 0; i < KT; ++i) {
      float x = (topv[i] > 0.5f) ? 1.0f : 0.0f;
      ce += (float)labels[i] * (x - lse);
    }
    ce = -ce;
    float pt = expf(-ce);
    float om = 1.0f - pt;
    float conf_loss = 0.25f * om * om * ce;   // ALPHA=0.25, GAMMA=2
    out[0] = (loc_loss + conf_loss) / (float)M;
  }
}

// ---------------- host ------------------------------------------------------

extern "C" void kernel_launch(void* const* d_in, const int* in_sizes, int n_in,
                              void* d_out, int out_size, void* d_ws, size_t ws_size,
                              hipStream_t stream) {
  (void)n_in; (void)out_size;
  const float* loc    = (const float*)d_in[0];
  const float* conf   = (const float*)d_in[1];
  const float* tb     = (const float*)d_in[2];
  const int*   labels = (const int*)d_in[3];
  float* out = (float*)d_out;

  int N = in_sizes[0] / 4;
  if (N > NCAP) N = NCAP;
  int C  = (N > 0) ? (in_sizes[1] / N) : 20;
  int KT = in_sizes[3];

  char* ws = (char*)d_ws;
  unsigned int* cnt   = (unsigned int*)(ws + OFF_CNT);
  u64*          keys  = (u64*)(ws + OFF_KEYS);
  float*        sx1   = (float*)(ws + OFF_SX1);
  float*        sy1   = (float*)(ws + OFF_SY1);
  float*        sx2   = (float*)(ws + OFF_SX2);
  float*        sy2   = (float*)(ws + OFF_SY2);
  float*        sarea = (float*)(ws + OFF_AREA);
  unsigned int* sorig = (unsigned int*)(ws + OFF_SORIG);
  unsigned int* keeps = (unsigned int*)(ws + OFF_KEEPS);
  float*        topv  = (float*)(ws + OFF_TOPV);
  int*          topi  = (int*)(ws + OFF_TOPI);
  u64*          diagI = (u64*)(ws + OFF_DIAG2);
  u64*          mask  = (u64*)(ws + OFF_MASK);

  bool use_mask = (ws_size >= WS_NEED_MASK);

  k_psort<<<16, 64, 0, stream>>>(conf, N, C, keys);
  k_merge<<<1, 1024, 0, stream>>>(loc, keys, cnt,
                                  sx1, sy1, sx2, sy2, sarea, sorig);
  if (use_mask) {
    k_mask<<<dim3(WROW, WROW), 64, 0, stream>>>(sx1, sy1, sx2, sy2, sarea,
                                                mask, diagI);
    k_scan<<<1, 1024, 0, stream>>>(mask, diagI, cnt, keeps);
  } else {
    k_scan_nomask<<<1, 256, 0, stream>>>(sx1, sy1, sx2, sy2, sarea, cnt, keeps);
  }
  k_topk<<<C, 1024, 0, stream>>>(conf, sorig, keeps, cnt, C, KT, topv, topi);
  k_loss<<<1, 256, 0, stream>>>(loc, tb, labels, sorig, keeps, topv, topi, cnt, C, KT, out);
}